// Round 3
// baseline (160.644 us; speedup 1.0000x reference)
//
#include <hip/hip_runtime.h>

#define NEURONS 8192
#define INSIZE  8192
#define BATCH   2048
#define ROWS    2          // batch rows per tile
#define TPB     1024       // 16 waves/block, 1 persistent block per CU
#define TILES   4          // tiles per block: 256 blocks * 4 * 2 rows = 2048
#define NPAIR   4          // neuron pairs per thread: 8192 / 2 / 1024
#define STV     (ROWS*INSIZE/4/TPB)   // staging f4 loads per thread = 4

using f4 = __attribute__((ext_vector_type(4))) float;
using f2 = __attribute__((ext_vector_type(2))) float;
using i4 = __attribute__((ext_vector_type(4))) int;

// Per-neuron softmax over 16 gate logits -> affine coefficients.
// Every logic op is affine in {1, a1, a2, a1*a2}:
//   out[b,n] = C0 + C1*a1 + C2*a2 + C3*(a1*a2)
__device__ __forceinline__ f4 softmax_coef(const float* __restrict__ wp) {
    const f4* w4 = reinterpret_cast<const f4*>(wp);
    f4 v0 = w4[0], v1 = w4[1], v2 = w4[2], v3 = w4[3];
    float p[16] = {v0.x, v0.y, v0.z, v0.w,
                   v1.x, v1.y, v1.z, v1.w,
                   v2.x, v2.y, v2.z, v2.w,
                   v3.x, v3.y, v3.z, v3.w};
    float m = p[0];
    #pragma unroll
    for (int i = 1; i < 16; ++i) m = fmaxf(m, p[i]);
    float s = 0.f;
    #pragma unroll
    for (int i = 0; i < 16; ++i) { p[i] = __expf(p[i] - m); s += p[i]; }
    float inv = 1.f / s;

    f4 c;
    c.x = (p[8] + p[9] + p[10] + p[11] + p[12] + p[13] + p[14] + p[15]) * inv;
    c.y = (p[2] + p[3] + p[6] + p[7] - p[8] - p[9] - p[12] - p[13]) * inv;
    c.z = (p[4] + p[5] + p[6] + p[7] - p[8] - p[9] - p[10] - p[11]) * inv;
    c.w = (p[1] - p[2] - p[4] - 2.f * p[6] - p[7]
         + p[8] + 2.f * p[9] + p[11] + p[13] - p[14]) * inv;
    return c;
}

// Persistent fused kernel: 1 block/CU, 4 tiles of 2 rows each,
// double-buffered LDS + register prefetch of the next tile.
__global__ __launch_bounds__(TPB, 4) void logic_fused_kernel(
        const float* __restrict__ x,
        const float* __restrict__ w,
        const int*   __restrict__ idx,
        float*       __restrict__ out) {
    __shared__ float xs[2][ROWS * INSIZE];   // 2 x 64 KiB

    const int tid  = threadIdx.x;
    const int row0 = blockIdx.x * (TILES * ROWS);

    // --- Prologue: issue tile-0 staging loads (in flight during softmax) ---
    f4 st[STV];
    {
        const f4* xt = reinterpret_cast<const f4*>(x + (size_t)row0 * INSIZE);
        #pragma unroll
        for (int i = 0; i < STV; ++i)
            st[i] = __builtin_nontemporal_load(&xt[tid + i * TPB]);
    }

    // --- Per-thread metadata (once per block), hides staging latency ---
    i4 ii[NPAIR]; f4 ca[NPAIR], cb[NPAIR];
    const i4* idx4 = reinterpret_cast<const i4*>(idx);
    #pragma unroll
    for (int k = 0; k < NPAIR; ++k) {
        const int t = tid + k * TPB;
        ii[k] = idx4[t];
        ca[k] = softmax_coef(w + (size_t)(2 * t)     * 16);
        cb[k] = softmax_coef(w + (size_t)(2 * t + 1) * 16);
    }

    // --- Commit tile 0 to LDS buffer 0 ---
    {
        f4* b = reinterpret_cast<f4*>(xs[0]);
        #pragma unroll
        for (int i = 0; i < STV; ++i) b[tid + i * TPB] = st[i];
    }
    __syncthreads();

    // --- Main pipeline: prefetch t+1 to regs, compute t from LDS ---
    #pragma unroll
    for (int t = 0; t < TILES; ++t) {
        if (t + 1 < TILES) {
            const f4* xt = reinterpret_cast<const f4*>(
                x + (size_t)(row0 + (t + 1) * ROWS) * INSIZE);
            #pragma unroll
            for (int i = 0; i < STV; ++i)
                st[i] = __builtin_nontemporal_load(&xt[tid + i * TPB]);
        }

        const float* xr0 = xs[t & 1];
        float* o0 = out + (size_t)(row0 + t * ROWS) * NEURONS;

        #pragma unroll
        for (int k = 0; k < NPAIR; ++k) {
            const int n = 2 * (tid + k * TPB);
            const i4 p = ii[k];
            const f4 u = ca[k];
            const f4 v = cb[k];
            #pragma unroll
            for (int r = 0; r < ROWS; ++r) {
                const float* xr = xr0 + r * INSIZE;
                const float a1 = xr[p.x];
                const float a2 = xr[p.y];
                const float b1 = xr[p.z];
                const float b2 = xr[p.w];
                f2 o;
                o.x = u.x + u.y * a1 + u.z * a2 + u.w * (a1 * a2);
                o.y = v.x + v.y * b1 + v.z * b2 + v.w * (b1 * b2);
                __builtin_nontemporal_store(o,
                    reinterpret_cast<f2*>(&o0[(size_t)r * NEURONS + n]));
            }
        }

        if (t + 1 < TILES) {
            f4* bn = reinterpret_cast<f4*>(xs[(t + 1) & 1]);
            #pragma unroll
            for (int i = 0; i < STV; ++i) bn[tid + i * TPB] = st[i];
            __syncthreads();
        }
    }
}

extern "C" void kernel_launch(void* const* d_in, const int* in_sizes, int n_in,
                              void* d_out, int out_size, void* d_ws, size_t ws_size,
                              hipStream_t stream) {
    const float* x   = (const float*)d_in[0];
    const float* w   = (const float*)d_in[1];
    const int*   idx = (const int*)d_in[2];
    float* out = (float*)d_out;

    logic_fused_kernel<<<BATCH / (TILES * ROWS), TPB, 0, stream>>>(x, w, idx, out);
}

// Round 4
// 123.987 us; speedup vs baseline: 1.2957x; 1.2957x over previous
//
#include <hip/hip_runtime.h>

#define NEURONS 8192
#define INSIZE  8192
#define BATCH   2048
#define ROWS    2          // batch rows staged (interleaved) in LDS per block
#define TPB     1024       // 16 waves/block, 2 blocks/CU -> 32 waves/CU

using f4 = __attribute__((ext_vector_type(4))) float;
using f2 = __attribute__((ext_vector_type(2))) float;
using i4 = __attribute__((ext_vector_type(4))) int;

// ---------------------------------------------------------------------------
// Kernel 1: per-neuron softmax over 16 gate logits -> 4 affine coefficients,
// stored SoA (C0[8192] | C1[8192] | C2[8192] | C3[8192]) for coalesced reads.
// Every logic op is affine in {1, a1, a2, a1*a2}:
//   out[b,n] = C0 + C1*a1 + C2*a2 + C3*(a1*a2)
// ---------------------------------------------------------------------------
__global__ __launch_bounds__(256) void coef_kernel(const float* __restrict__ w,
                                                   float* __restrict__ cf) {
    int n = blockIdx.x * blockDim.x + threadIdx.x;
    if (n >= NEURONS) return;

    const f4* w4 = reinterpret_cast<const f4*>(w + (size_t)n * 16);
    f4 v0 = w4[0], v1 = w4[1], v2 = w4[2], v3 = w4[3];
    float p[16] = {v0.x, v0.y, v0.z, v0.w,
                   v1.x, v1.y, v1.z, v1.w,
                   v2.x, v2.y, v2.z, v2.w,
                   v3.x, v3.y, v3.z, v3.w};

    float m = p[0];
    #pragma unroll
    for (int i = 1; i < 16; ++i) m = fmaxf(m, p[i]);
    float s = 0.f;
    #pragma unroll
    for (int i = 0; i < 16; ++i) { p[i] = __expf(p[i] - m); s += p[i]; }
    float inv = 1.f / s;

    cf[0 * NEURONS + n] = (p[8] + p[9] + p[10] + p[11]
                         + p[12] + p[13] + p[14] + p[15]) * inv;
    cf[1 * NEURONS + n] = (p[2] + p[3] + p[6] + p[7]
                         - p[8] - p[9] - p[12] - p[13]) * inv;
    cf[2 * NEURONS + n] = (p[4] + p[5] + p[6] + p[7]
                         - p[8] - p[9] - p[10] - p[11]) * inv;
    cf[3 * NEURONS + n] = (p[1] - p[2] - p[4] - 2.f * p[6] - p[7]
                         + p[8] + 2.f * p[9] + p[11] + p[13] - p[14]) * inv;
}

// ---------------------------------------------------------------------------
// Kernel 2: stage 2 x-rows ROW-INTERLEAVED in LDS (xs[c] = {row0[c],row1[c]}),
// so one ds_read_b64 serves a gathered column for both rows. Each thread
// handles 4 consecutive neurons -> f4 coalesced coef loads + f4 NT stores.
// ---------------------------------------------------------------------------
__global__ __launch_bounds__(TPB, 8) void logic_kernel(const float* __restrict__ x,
                                                       const int* __restrict__ idx,
                                                       const float* __restrict__ cf,
                                                       float* __restrict__ out) {
    __shared__ f2 xs[INSIZE];   // 64 KiB, interleaved pair per column

    const int tid = threadIdx.x;
    const int b0  = blockIdx.x * ROWS;

    // --- Stage: f2 loads from each row, one balanced ds_write_b128 each ---
    const f2* xr0 = reinterpret_cast<const f2*>(x + (size_t)b0 * INSIZE);
    const f2* xr1 = reinterpret_cast<const f2*>(x + (size_t)(b0 + 1) * INSIZE);
    f4* xs4 = reinterpret_cast<f4*>(xs);
    #pragma unroll
    for (int i = 0; i < INSIZE / 2 / TPB; ++i) {       // 4 iters
        const int c = tid + i * TPB;                   // f2-column index
        f2 a = __builtin_nontemporal_load(&xr0[c]);    // row0 cols {2c,2c+1}
        f2 b = __builtin_nontemporal_load(&xr1[c]);    // row1 cols {2c,2c+1}
        f4 v; v.x = a.x; v.y = b.x; v.z = a.y; v.w = b.y;
        xs4[c] = v;                                    // 16B stride: balanced banks
    }
    __syncthreads();

    float* o0 = out + (size_t)b0 * NEURONS;
    float* o1 = o0 + NEURONS;
    const i4* idx4 = reinterpret_cast<const i4*>(idx);
    const f4* C0 = reinterpret_cast<const f4*>(cf + 0 * NEURONS);
    const f4* C1 = reinterpret_cast<const f4*>(cf + 1 * NEURONS);
    const f4* C2 = reinterpret_cast<const f4*>(cf + 2 * NEURONS);
    const f4* C3 = reinterpret_cast<const f4*>(cf + 3 * NEURONS);

    #pragma unroll
    for (int k = 0; k < NEURONS / (TPB * 4); ++k) {    // 2 iters
        const int q = tid + k * TPB;                   // neuron-quad index
        const int n = 4 * q;
        const i4 iA = idx4[2 * q];                     // neurons n, n+1
        const i4 iB = idx4[2 * q + 1];                 // neurons n+2, n+3
        const f4 c0 = C0[q], c1 = C1[q], c2 = C2[q], c3 = C3[q];

        const f2 g0 = xs[iA.x], g1 = xs[iA.y];         // {row0,row1} pairs
        const f2 g2 = xs[iA.z], g3 = xs[iA.w];
        const f2 g4 = xs[iB.x], g5 = xs[iB.y];
        const f2 g6 = xs[iB.z], g7 = xs[iB.w];

        f4 r0, r1;
        r0.x = c0.x + c1.x * g0.x + c2.x * g1.x + c3.x * (g0.x * g1.x);
        r1.x = c0.x + c1.x * g0.y + c2.x * g1.y + c3.x * (g0.y * g1.y);
        r0.y = c0.y + c1.y * g2.x + c2.y * g3.x + c3.y * (g2.x * g3.x);
        r1.y = c0.y + c1.y * g2.y + c2.y * g3.y + c3.y * (g2.y * g3.y);
        r0.z = c0.z + c1.z * g4.x + c2.z * g5.x + c3.z * (g4.x * g5.x);
        r1.z = c0.z + c1.z * g4.y + c2.z * g5.y + c3.z * (g4.y * g5.y);
        r0.w = c0.w + c1.w * g6.x + c2.w * g7.x + c3.w * (g6.x * g7.x);
        r1.w = c0.w + c1.w * g6.y + c2.w * g7.y + c3.w * (g6.y * g7.y);

        __builtin_nontemporal_store(r0, reinterpret_cast<f4*>(&o0[n]));
        __builtin_nontemporal_store(r1, reinterpret_cast<f4*>(&o1[n]));
    }
}

extern "C" void kernel_launch(void* const* d_in, const int* in_sizes, int n_in,
                              void* d_out, int out_size, void* d_ws, size_t ws_size,
                              hipStream_t stream) {
    const float* x   = (const float*)d_in[0];
    const float* w   = (const float*)d_in[1];
    const int*   idx = (const int*)d_in[2];
    float* out = (float*)d_out;
    float* cf  = (float*)d_ws;    // 4 * 8192 * 4 B = 128 KiB SoA coefficients

    coef_kernel<<<NEURONS / 256, 256, 0, stream>>>(w, cf);
    logic_kernel<<<BATCH / ROWS, TPB, 0, stream>>>(x, idx, cf, out);
}

// Round 5
// 122.003 us; speedup vs baseline: 1.3167x; 1.0163x over previous
//
#include <hip/hip_runtime.h>

#define NEURONS 8192
#define INSIZE  8192
#define BATCH   2048
#define ROWS    4          // batch rows interleaved per LDS column
#define TPB     1024       // 16 waves/block, 1 block/CU (128 KiB LDS)

using f4 = __attribute__((ext_vector_type(4))) float;
using i4 = __attribute__((ext_vector_type(4))) int;

// ---------------------------------------------------------------------------
// Kernel 1: per-neuron softmax over 16 gate logits -> 4 affine coefficients,
// stored SoA (C0[8192] | C1[8192] | C2[8192] | C3[8192]) for coalesced reads.
// Every logic op is affine in {1, a1, a2, a1*a2}:
//   out[b,n] = C0 + C1*a1 + C2*a2 + C3*(a1*a2)
// ---------------------------------------------------------------------------
__global__ __launch_bounds__(64) void coef_kernel(const float* __restrict__ w,
                                                  float* __restrict__ cf) {
    int n = blockIdx.x * blockDim.x + threadIdx.x;
    if (n >= NEURONS) return;

    const f4* w4 = reinterpret_cast<const f4*>(w + (size_t)n * 16);
    f4 v0 = w4[0], v1 = w4[1], v2 = w4[2], v3 = w4[3];
    float p[16] = {v0.x, v0.y, v0.z, v0.w,
                   v1.x, v1.y, v1.z, v1.w,
                   v2.x, v2.y, v2.z, v2.w,
                   v3.x, v3.y, v3.z, v3.w};

    float m = p[0];
    #pragma unroll
    for (int i = 1; i < 16; ++i) m = fmaxf(m, p[i]);
    float s = 0.f;
    #pragma unroll
    for (int i = 0; i < 16; ++i) { p[i] = __expf(p[i] - m); s += p[i]; }
    float inv = 1.f / s;

    cf[0 * NEURONS + n] = (p[8] + p[9] + p[10] + p[11]
                         + p[12] + p[13] + p[14] + p[15]) * inv;
    cf[1 * NEURONS + n] = (p[2] + p[3] + p[6] + p[7]
                         - p[8] - p[9] - p[12] - p[13]) * inv;
    cf[2 * NEURONS + n] = (p[4] + p[5] + p[6] + p[7]
                         - p[8] - p[9] - p[10] - p[11]) * inv;
    cf[3 * NEURONS + n] = (p[1] - p[2] - p[4] - 2.f * p[6] - p[7]
                         + p[8] + 2.f * p[9] + p[11] + p[13] - p[14]) * inv;
}

// ---------------------------------------------------------------------------
// Kernel 2: stage 4 x-rows ROW-INTERLEAVED in LDS (xs[c] = {r0,r1,r2,r3}[c]),
// so one ds_read_b128 serves a gathered column for all 4 rows. Each thread
// handles 4 consecutive neurons -> f4 coalesced idx/coef loads, f4 NT stores.
// 512 blocks (1/CU x 2 rounds): halved idx/cf L2 traffic + gather count.
// ---------------------------------------------------------------------------
__global__ __launch_bounds__(TPB, 4) void logic_kernel(const float* __restrict__ x,
                                                       const int* __restrict__ idx,
                                                       const float* __restrict__ cf,
                                                       float* __restrict__ out) {
    __shared__ f4 xs[INSIZE];   // 128 KiB: column-major 4-row interleave

    const int tid = threadIdx.x;
    const int b0  = blockIdx.x * ROWS;
    const float* xb = x + (size_t)b0 * INSIZE;

    // --- Stage: per iter, f4 from each of 4 rows, 4x4 register transpose,
    //     4 ds_write_b128 at uniform 64B lane stride (bank-balanced). ---
    #pragma unroll
    for (int i = 0; i < INSIZE / 4 / TPB; ++i) {       // 2 iters
        const int c = tid + i * TPB;                   // f4-column group
        f4 r0 = __builtin_nontemporal_load(
                    reinterpret_cast<const f4*>(xb + 0 * INSIZE) + c);
        f4 r1 = __builtin_nontemporal_load(
                    reinterpret_cast<const f4*>(xb + 1 * INSIZE) + c);
        f4 r2 = __builtin_nontemporal_load(
                    reinterpret_cast<const f4*>(xb + 2 * INSIZE) + c);
        f4 r3 = __builtin_nontemporal_load(
                    reinterpret_cast<const f4*>(xb + 3 * INSIZE) + c);
        #pragma unroll
        for (int j = 0; j < 4; ++j) {
            f4 v; v.x = r0[j]; v.y = r1[j]; v.z = r2[j]; v.w = r3[j];
            xs[4 * c + j] = v;
        }
    }
    __syncthreads();

    float* o0 = out + (size_t)b0 * NEURONS;
    const i4* idx4 = reinterpret_cast<const i4*>(idx);
    const f4* C0 = reinterpret_cast<const f4*>(cf + 0 * NEURONS);
    const f4* C1 = reinterpret_cast<const f4*>(cf + 1 * NEURONS);
    const f4* C2 = reinterpret_cast<const f4*>(cf + 2 * NEURONS);
    const f4* C3 = reinterpret_cast<const f4*>(cf + 3 * NEURONS);

    #pragma unroll
    for (int k = 0; k < NEURONS / (TPB * 4); ++k) {    // 2 iters
        const int q = tid + k * TPB;                   // neuron-quad index
        const int n = 4 * q;
        const i4 iA = idx4[2 * q];                     // neurons n, n+1
        const i4 iB = idx4[2 * q + 1];                 // neurons n+2, n+3
        const f4 c0 = C0[q], c1 = C1[q], c2 = C2[q], c3 = C3[q];

        // One b128 gather = that column for all 4 rows.
        const f4 gA0 = xs[iA.x], gB0 = xs[iA.y];       // neuron n
        const f4 gA1 = xs[iA.z], gB1 = xs[iA.w];       // neuron n+1
        const f4 gA2 = xs[iB.x], gB2 = xs[iB.y];       // neuron n+2
        const f4 gA3 = xs[iB.z], gB3 = xs[iB.w];       // neuron n+3

        #pragma unroll
        for (int r = 0; r < ROWS; ++r) {
            f4 o;
            o.x = c0.x + c1.x * gA0[r] + c2.x * gB0[r] + c3.x * (gA0[r] * gB0[r]);
            o.y = c0.y + c1.y * gA1[r] + c2.y * gB1[r] + c3.y * (gA1[r] * gB1[r]);
            o.z = c0.z + c1.z * gA2[r] + c2.z * gB2[r] + c3.z * (gA2[r] * gB2[r]);
            o.w = c0.w + c1.w * gA3[r] + c2.w * gB3[r] + c3.w * (gA3[r] * gB3[r]);
            __builtin_nontemporal_store(o,
                reinterpret_cast<f4*>(&o0[(size_t)r * NEURONS + n]));
        }
    }
}

extern "C" void kernel_launch(void* const* d_in, const int* in_sizes, int n_in,
                              void* d_out, int out_size, void* d_ws, size_t ws_size,
                              hipStream_t stream) {
    const float* x   = (const float*)d_in[0];
    const float* w   = (const float*)d_in[1];
    const int*   idx = (const int*)d_in[2];
    float* out = (float*)d_out;
    float* cf  = (float*)d_ws;    // 4 * 8192 * 4 B = 128 KiB SoA coefficients

    coef_kernel<<<NEURONS / 64, 64, 0, stream>>>(w, cf);
    logic_kernel<<<BATCH / ROWS, TPB, 0, stream>>>(x, idx, cf, out);
}